// Round 3
// baseline (303.896 us; speedup 1.0000x reference)
//
#include <hip/hip_runtime.h>

#define N_NODES 50000
#define N_EDGES 800000
#define D 128
#define TN 16                 // nodes per block in the fused layer kernel (4 waves)
#define TSTR 136              // LDS row stride in bf16 elems (272B: 16B-aligned)
#define EDGE_BLOCKS 3125      // N_EDGES / 256
#define ZROW N_NODES          // index of the all-zeros dummy row appended to each h buffer

typedef __attribute__((ext_vector_type(8))) short bf16x8;
typedef __attribute__((ext_vector_type(4))) float f32x4;

__device__ __forceinline__ unsigned short f32_to_bf16_rne(float f) {
    unsigned u = __float_as_uint(f);
    u += 0x7fffu + ((u >> 16) & 1u);
    return (unsigned short)(u >> 16);
}

__device__ __forceinline__ float bflo(unsigned u) { return __uint_as_float(u << 16); }
__device__ __forceinline__ float bfhi(unsigned u) { return __uint_as_float(u & 0xffff0000u); }

__device__ __forceinline__ void acc8(uint4 r, float* a) {
    a[0] += bflo(r.x); a[1] += bfhi(r.x);
    a[2] += bflo(r.y); a[3] += bfhi(r.y);
    a[4] += bflo(r.z); a[5] += bfhi(r.z);
    a[6] += bflo(r.w); a[7] += bfhi(r.w);
}

// Half-wave gather step: 8 slot-groups of 2 edges (16 edges). Within a 32-lane
// half: rowid2 = (lane>>4)&1 selects even/odd edge of the slot, d8 = lane&15
// selects the 8-dim octet -> one uint4 (16B) load covers 8 dims; 16 lanes
// cover a row. 8 independent 16B row-loads in flight per thread.
// Slots past the real edge count carry index ZROW (all-zeros row): the load
// is L1-hot and accumulates +0 -- no tail branches needed.
__device__ __forceinline__ void gather16x8(const unsigned short* __restrict__ hb,
                                           int myidx, int i, int rowid2, int d8,
                                           float* a0, float* a1) {
    int si[8];
    uint4 rr[8];
#pragma unroll
    for (int u = 0; u < 8; ++u) si[u] = __shfl(myidx, i + 2 * u + rowid2, 32);
#pragma unroll
    for (int u = 0; u < 8; ++u) rr[u] = *(const uint4*)(hb + (size_t)si[u] * D + 8 * d8);
#pragma unroll
    for (int u = 0; u < 8; ++u) acc8(rr[u], (u & 1) ? a1 : a0);
}

// Gather-sum of h[src] over one node's edge list, executed by a 32-lane half.
// idx0 = preloaded first index chunk (<=32 edges, ZROW-padded). Result:
// out[0..7] = full row sums for dims 8*d8 .. 8*d8+7 (all lanes, after xor16).
__device__ __forceinline__ void gather_node(const unsigned short* __restrict__ hb,
                                            const unsigned short* __restrict__ esrc,
                                            int beg, int deg, int idx0,
                                            int l32, int rowid2, int d8,
                                            float* out) {
    float a0[8] = {0.f, 0.f, 0.f, 0.f, 0.f, 0.f, 0.f, 0.f};
    float a1[8] = {0.f, 0.f, 0.f, 0.f, 0.f, 0.f, 0.f, 0.f};
    int myidx = idx0;
    int base = 0;
    while (true) {
        const int cnt = min(deg - base, 32);
        for (int i = 0; i < cnt; i += 16)
            gather16x8(hb, myidx, i, rowid2, d8, a0, a1);
        base += 32;
        if (base >= deg) break;             // cold path: deg > 32 chunks
        myidx = ZROW;
        if (l32 < deg - base) myidx = (int)esrc[beg + base + l32];
    }
#pragma unroll
    for (int k = 0; k < 8; ++k) {
        float s = a0[k] + a1[k];
        s += __shfl_xor(s, 16, 64);         // combine the two edge-parity rows
        out[k] = s;
    }
}

// ---------------------------------------------------------------------------
// prep (blocks 0..3124): rank[e] = position of edge e within its dst bucket
//       AND x fp32 -> bf16 (8 elems/thread; 800K threads = all 6.4M elems)
//       AND zero the dummy ZROW row of xb/h1/h2.
// prep (blocks 3125..3316): pack all 3 weights as bf16 MFMA B-fragments.
//   B[k][n] for tile nt, chunk kc at Wb[((w*8+nt)*4+kc)*512 + lane*8 + j],
//   lane = quad*16+n, k = kc*32+quad*8+j, B[k][n] = W[nt*16+n][k].
// ---------------------------------------------------------------------------
__global__ void prep_kernel(const int* __restrict__ dst, int* __restrict__ counts,
                            unsigned short* __restrict__ rank,
                            const float* __restrict__ x, unsigned short* __restrict__ xb,
                            unsigned short* __restrict__ h1, unsigned short* __restrict__ h2,
                            const float* __restrict__ W1, const float* __restrict__ W2,
                            const float* __restrict__ W3, unsigned short* __restrict__ Wb) {
    if (blockIdx.x >= EDGE_BLOCKS) {
        const int unit = (blockIdx.x - EDGE_BLOCKS) * 2 + (threadIdx.x >> 7); // 0..383
        const int w = unit >> 7;
        const int o = unit & 127;
        const int k = threadIdx.x & 127;
        const float* W = (w == 0) ? W1 : (w == 1) ? W2 : W3;
        const unsigned short v = f32_to_bf16_rne(W[o * D + k]);
        const int nt = o >> 4, n = o & 15;
        const int kc = k >> 5, kr = k & 31, quad = kr >> 3, j = kr & 7;
        const int lane = quad * 16 + n;
        Wb[(((size_t)w * 8 + nt) * 4 + kc) * 512 + lane * 8 + j] = v;
        return;
    }
    const int t = blockIdx.x * blockDim.x + threadIdx.x;
    rank[t] = (unsigned short)atomicAdd(&counts[dst[t]], 1);
    {
        const float4 v0 = *(const float4*)(x + (size_t)t * 8);
        const float4 v1 = *(const float4*)(x + (size_t)t * 8 + 4);
        uint4 p;
        p.x = (unsigned)f32_to_bf16_rne(v0.x) | ((unsigned)f32_to_bf16_rne(v0.y) << 16);
        p.y = (unsigned)f32_to_bf16_rne(v0.z) | ((unsigned)f32_to_bf16_rne(v0.w) << 16);
        p.z = (unsigned)f32_to_bf16_rne(v1.x) | ((unsigned)f32_to_bf16_rne(v1.y) << 16);
        p.w = (unsigned)f32_to_bf16_rne(v1.z) | ((unsigned)f32_to_bf16_rne(v1.w) << 16);
        *(uint4*)(xb + (size_t)t * 8) = p;
    }
    if (blockIdx.x == 0 && threadIdx.x < 48) {
        const int rowsel = threadIdx.x >> 4;       // 0,1,2 -> xb,h1,h2
        const int off = threadIdx.x & 15;          // 16 x 16B = 256B row
        unsigned short* zp = (rowsel == 0) ? xb : (rowsel == 1) ? h1 : h2;
        *(uint4*)(zp + (size_t)ZROW * D + off * 8) = make_uint4(0u, 0u, 0u, 0u);
    }
}

// ---------------------------------------------------------------------------
// Single-block exclusive scan of counts[50000] -> offsets[50001].
// 1024 threads x 49-element chunks; data is L2-hot from prep. Replaces the
// previous 3-dispatch scan chain (block_sum + bsum_scan + scan-C).
// ---------------------------------------------------------------------------
#define SCAN_CHUNK 49
__global__ __launch_bounds__(1024) void scan_kernel(const int* __restrict__ counts,
                                                    int* __restrict__ offsets) {
    __shared__ int ssum[1024];
    const int tid = threadIdx.x;
    const int beg = tid * SCAN_CHUNK;
    int s = 0;
    const int rend = min(beg + SCAN_CHUNK, N_NODES);
    for (int i = beg; i < rend; ++i) s += counts[i];
    ssum[tid] = s;
    __syncthreads();
    for (int off = 1; off < 1024; off <<= 1) {
        int a = (tid >= off) ? ssum[tid - off] : 0;
        __syncthreads();
        ssum[tid] += a;
        __syncthreads();
    }
    int run = ssum[tid] - s;                       // exclusive prefix
    const int wend = min(beg + SCAN_CHUNK, N_NODES + 1);
    for (int i = beg; i < wend; ++i) {
        offsets[i] = run;
        if (i < N_NODES) run += counts[i];
    }
}

// ---------------------------------------------------------------------------
// CSR fill, atomic-free: esrc[offsets[dst[e]] + rank[e]] = src[e]  (ushort)
// ---------------------------------------------------------------------------
__global__ void fill_kernel(const int* __restrict__ src, const int* __restrict__ dst,
                            const unsigned short* __restrict__ rank,
                            const int* __restrict__ offsets,
                            unsigned short* __restrict__ esrc) {
    int e = blockIdx.x * blockDim.x + threadIdx.x;
    if (e < N_EDGES) {
        esrc[offsets[dst[e]] + (int)rank[e]] = (unsigned short)src[e];
    }
}

// ---------------------------------------------------------------------------
// Fused layer: out[v] = (sum h[src_e] - deg[v]*h[v]) @ W^T + deg[v]*b
// Block = 256 threads (4 waves), TN=16 nodes/block, 3125 blocks (best-measured
// geometry, R1). Phase 1 gather: each 32-lane half-wave owns an independent
// 2-node stream (8 half-wave streams/block). Rows read as uint4 (16B, 8
// dims/lane, 16 lanes/row); 8 x 16B row loads in flight per thread. Slots past
// the edge count use the ZROW all-zeros dummy row (L1-hot, adds 0.0) --
// tail-branch-free inner loop. Both nodes' esrc index chunks prefetched
// up-front. Finalize: rowid2==0 lanes -> node A, rowid2==1 -> node B;
// t -> LDS bf16.
// Phase 2: 16x128x128 GEMM via 8 v_mfma_f32_16x16x32_bf16 per wave (all 16
// C-rows used).
// ---------------------------------------------------------------------------
template <bool OUT_BF16>
__global__ __launch_bounds__(256) void gnn_layer_kernel(
    const unsigned short* __restrict__ hb,     // [N+pad][D] bf16, row ZROW = zeros
    const int* __restrict__ offsets,
    const unsigned short* __restrict__ esrc,
    const unsigned short* __restrict__ Wb,     // fragment-ordered bf16 (this layer)
    const float* __restrict__ bias,
    float* __restrict__ outf,
    unsigned short* __restrict__ outb) {

    __shared__ __align__(16) unsigned short tb[TN][TSTR];
    __shared__ float degf[TN];

    const int tid = threadIdx.x;
    const int wave = tid >> 6;
    const int lane = tid & 63;
    const int half = lane >> 5;          // which 32-lane half
    const int l32 = lane & 31;
    const int rowid2 = (lane >> 4) & 1;  // edge parity within slot
    const int d8 = lane & 15;            // dim octet: dims 8*d8 .. 8*d8+7
    const int vbase = blockIdx.x * TN;

    // ---- phase 1: gather (2 nodes per half-wave, serial) ----
    const int j0 = wave * 4 + half * 2;
    const int v0 = vbase + j0;

    const int begA = offsets[v0];
    const int begB = offsets[v0 + 1];
    const int degA = begB - begA;
    const int degB = offsets[v0 + 2] - begB;

    // prefetch both nodes' first index chunks (two loads in flight)
    int idxA = ZROW, idxB = ZROW;
    if (l32 < min(degA, 32)) idxA = (int)esrc[begA + l32];
    if (l32 < min(degB, 32)) idxB = (int)esrc[begB + l32];

    float sA[8], sB[8];
    gather_node(hb, esrc, begA, degA, idxA, l32, rowid2, d8, sA);
    gather_node(hb, esrc, begB, degB, idxB, l32, rowid2, d8, sB);

    // finalize: rowid2==0 lanes -> node A, rowid2==1 lanes -> node B
    {
        const int vv = v0 + rowid2;
        const float dv = (float)(rowid2 ? degB : degA);
        const uint4 r = *(const uint4*)(hb + (size_t)vv * D + 8 * d8);
        float t[8];
#pragma unroll
        for (int k = 0; k < 8; ++k) t[k] = rowid2 ? sB[k] : sA[k];
        t[0] -= dv * bflo(r.x); t[1] -= dv * bfhi(r.x);
        t[2] -= dv * bflo(r.y); t[3] -= dv * bfhi(r.y);
        t[4] -= dv * bflo(r.z); t[5] -= dv * bfhi(r.z);
        t[6] -= dv * bflo(r.w); t[7] -= dv * bfhi(r.w);
        uint4 p;
        p.x = (unsigned)f32_to_bf16_rne(t[0]) | ((unsigned)f32_to_bf16_rne(t[1]) << 16);
        p.y = (unsigned)f32_to_bf16_rne(t[2]) | ((unsigned)f32_to_bf16_rne(t[3]) << 16);
        p.z = (unsigned)f32_to_bf16_rne(t[4]) | ((unsigned)f32_to_bf16_rne(t[5]) << 16);
        p.w = (unsigned)f32_to_bf16_rne(t[6]) | ((unsigned)f32_to_bf16_rne(t[7]) << 16);
        *(uint4*)&tb[j0 + rowid2][8 * d8] = p;
        if (d8 == 0) degf[j0 + rowid2] = dv;
    }
    __syncthreads();

    // ---- phase 2: MFMA GEMM  out[16][128] = t[16][128] @ Wt[128][128] ----
    const int n16 = lane & 15;
    const int quad = lane >> 4;

    bf16x8 afrag[4];
#pragma unroll
    for (int kc = 0; kc < 4; ++kc)
        afrag[kc] = *(const bf16x8*)&tb[n16][kc * 32 + quad * 8];

#pragma unroll
    for (int i = 0; i < 2; ++i) {
        const int nt = wave * 2 + i;
        f32x4 acc = {0.f, 0.f, 0.f, 0.f};
#pragma unroll
        for (int kc = 0; kc < 4; ++kc) {
            const bf16x8 bfrag = *(const bf16x8*)&Wb[((nt * 4 + kc) * 64 + lane) * 8];
            acc = __builtin_amdgcn_mfma_f32_16x16x32_bf16(afrag[kc], bfrag, acc, 0, 0, 0);
        }
        const int o = nt * 16 + n16;
        const float bo = bias[o];
#pragma unroll
        for (int r = 0; r < 4; ++r) {
            const int m = quad * 4 + r;
            const float val = acc[r] + degf[m] * bo;
            if (OUT_BF16)
                outb[(size_t)(vbase + m) * D + o] = f32_to_bf16_rne(val);
            else
                outf[(size_t)(vbase + m) * D + o] = val;
        }
    }
}

extern "C" void kernel_launch(void* const* d_in, const int* in_sizes, int n_in,
                              void* d_out, int out_size, void* d_ws, size_t ws_size,
                              hipStream_t stream) {
    const float* x  = (const float*)d_in[0];
    const float* W1 = (const float*)d_in[1];
    const float* b1 = (const float*)d_in[2];
    const float* W2 = (const float*)d_in[3];
    const float* b2 = (const float*)d_in[4];
    const float* W3 = (const float*)d_in[5];
    const float* b3 = (const float*)d_in[6];
    const int*   ei = (const int*)d_in[7];      // [2, E] int32
    // d_in[8] = edge_index_inter — unused by the reference

    const int* src = ei;            // row 0
    const int* dst = ei + N_EDGES;  // row 1
    float* out = (float*)d_out;

    // workspace layout (256B-aligned slabs); h-buffers have +2 rows for ZROW
    const size_t HSLAB = (size_t)(N_NODES + 2) * D * 2;
    char* ws = (char*)d_ws;
    int* counts  = (int*)ws;                          ws += 204800;               // N ints
    int* offsets = (int*)ws;                          ws += 204800;               // N+1 ints
    unsigned short* rank = (unsigned short*)ws;       ws += (size_t)N_EDGES * 2;  // 1.6MB
    unsigned short* esrc = (unsigned short*)ws;       ws += (size_t)N_EDGES * 2;  // 1.6MB
    unsigned short* Wb = (unsigned short*)ws;         ws += 3 * 16384 * 2;        // 96KB
    unsigned short* xb = (unsigned short*)ws;         ws += HSLAB;
    unsigned short* h1 = (unsigned short*)ws;         ws += HSLAB;
    unsigned short* h2 = (unsigned short*)ws;

    // ---- CSR build + cvt + weight pack (3 dispatches + memset) ----
    hipMemsetAsync(counts, 0, N_NODES * sizeof(int), stream);
    prep_kernel<<<EDGE_BLOCKS + 192, 256, 0, stream>>>(dst, counts, rank, x, xb, h1, h2,
                                                       W1, W2, W3, Wb);
    scan_kernel<<<1, 1024, 0, stream>>>(counts, offsets);
    fill_kernel<<<(N_EDGES + 255) / 256, 256, 0, stream>>>(src, dst, rank, offsets, esrc);

    const int blocks = N_NODES / TN;   // 3125

    gnn_layer_kernel<true ><<<blocks, 256, 0, stream>>>(xb, offsets, esrc, Wb,          b1, nullptr, h1);
    gnn_layer_kernel<true ><<<blocks, 256, 0, stream>>>(h1, offsets, esrc, Wb + 16384,  b2, nullptr, h2);
    gnn_layer_kernel<false><<<blocks, 256, 0, stream>>>(h2, offsets, esrc, Wb + 32768,  b3, out, nullptr);
}

// Round 5
// 233.939 us; speedup vs baseline: 1.2990x; 1.2990x over previous
//
#include <hip/hip_runtime.h>

#define N_NODES 50000
#define N_EDGES 800000
#define D 128
#define TN 16                 // nodes per block in the fused layer kernel (4 waves)
#define TSTR 136              // LDS row stride in bf16 elems (272B: 16B-aligned)
#define EDGE_BLOCKS 3125      // N_EDGES / 256
#define SCAN_BLOCKS 196       // ceil(50000/256)
#define ZROW N_NODES          // index of the all-zeros dummy row appended to each h buffer

typedef __attribute__((ext_vector_type(8))) short bf16x8;
typedef __attribute__((ext_vector_type(4))) float f32x4;

__device__ __forceinline__ unsigned short f32_to_bf16_rne(float f) {
    unsigned u = __float_as_uint(f);
    u += 0x7fffu + ((u >> 16) & 1u);
    return (unsigned short)(u >> 16);
}

__device__ __forceinline__ float bflo(unsigned u) { return __uint_as_float(u << 16); }
__device__ __forceinline__ float bfhi(unsigned u) { return __uint_as_float(u & 0xffff0000u); }

__device__ __forceinline__ void acc8(uint4 r, float* a) {
    a[0] += bflo(r.x); a[1] += bfhi(r.x);
    a[2] += bflo(r.y); a[3] += bfhi(r.y);
    a[4] += bflo(r.z); a[5] += bfhi(r.z);
    a[6] += bflo(r.w); a[7] += bfhi(r.w);
}

// Half-wave gather step: 8 slot-groups of 2 edges (16 edges). Within a 32-lane
// half: rowid2 = (lane>>4)&1 selects even/odd edge of the slot, d8 = lane&15
// selects the 8-dim octet -> one uint4 (16B) load covers 8 dims; 16 lanes
// cover a row. 8 independent 16B row-loads in flight per thread.
// Slots past the real edge count carry index ZROW (all-zeros row): the load
// is L1-hot and accumulates +0 -- no tail branches needed.
__device__ __forceinline__ void gather16x8(const unsigned short* __restrict__ hb,
                                           int myidx, int i, int rowid2, int d8,
                                           float* a0, float* a1) {
    int si[8];
    uint4 rr[8];
#pragma unroll
    for (int u = 0; u < 8; ++u) si[u] = __shfl(myidx, i + 2 * u + rowid2, 32);
#pragma unroll
    for (int u = 0; u < 8; ++u) rr[u] = *(const uint4*)(hb + (size_t)si[u] * D + 8 * d8);
#pragma unroll
    for (int u = 0; u < 8; ++u) acc8(rr[u], (u & 1) ? a1 : a0);
}

// Gather-sum of h[src] over one node's edge list, executed by a 32-lane half.
// idx0 = preloaded first index chunk (<=32 edges, ZROW-padded). Result:
// out[0..7] = full row sums for dims 8*d8 .. 8*d8+7 (all lanes, after xor16).
__device__ __forceinline__ void gather_node(const unsigned short* __restrict__ hb,
                                            const unsigned short* __restrict__ esrc,
                                            int beg, int deg, int idx0,
                                            int l32, int rowid2, int d8,
                                            float* out) {
    float a0[8] = {0.f, 0.f, 0.f, 0.f, 0.f, 0.f, 0.f, 0.f};
    float a1[8] = {0.f, 0.f, 0.f, 0.f, 0.f, 0.f, 0.f, 0.f};
    int myidx = idx0;
    int base = 0;
    while (true) {
        const int cnt = min(deg - base, 32);
        for (int i = 0; i < cnt; i += 16)
            gather16x8(hb, myidx, i, rowid2, d8, a0, a1);
        base += 32;
        if (base >= deg) break;             // cold path: deg > 32 chunks
        myidx = ZROW;
        if (l32 < deg - base) myidx = (int)esrc[beg + base + l32];
    }
#pragma unroll
    for (int k = 0; k < 8; ++k) {
        float s = a0[k] + a1[k];
        s += __shfl_xor(s, 16, 64);         // combine the two edge-parity rows
        out[k] = s;
    }
}

// ---------------------------------------------------------------------------
// prep (blocks 0..3124): rank[e] = position of edge e within its dst bucket
//       AND x fp32 -> bf16 (8 elems/thread; 800K threads = all 6.4M elems)
//       AND zero the dummy ZROW row of xb/h1/h2.
// prep (blocks 3125..3316): pack all 3 weights as bf16 MFMA B-fragments.
//   B[k][n] for tile nt, chunk kc at Wb[((w*8+nt)*4+kc)*512 + lane*8 + j],
//   lane = quad*16+n, k = kc*32+quad*8+j, B[k][n] = W[nt*16+n][k].
// ---------------------------------------------------------------------------
__global__ void prep_kernel(const int* __restrict__ dst, int* __restrict__ counts,
                            unsigned short* __restrict__ rank,
                            const float* __restrict__ x, unsigned short* __restrict__ xb,
                            unsigned short* __restrict__ h1, unsigned short* __restrict__ h2,
                            const float* __restrict__ W1, const float* __restrict__ W2,
                            const float* __restrict__ W3, unsigned short* __restrict__ Wb) {
    if (blockIdx.x >= EDGE_BLOCKS) {
        const int unit = (blockIdx.x - EDGE_BLOCKS) * 2 + (threadIdx.x >> 7); // 0..383
        const int w = unit >> 7;
        const int o = unit & 127;
        const int k = threadIdx.x & 127;
        const float* W = (w == 0) ? W1 : (w == 1) ? W2 : W3;
        const unsigned short v = f32_to_bf16_rne(W[o * D + k]);
        const int nt = o >> 4, n = o & 15;
        const int kc = k >> 5, kr = k & 31, quad = kr >> 3, j = kr & 7;
        const int lane = quad * 16 + n;
        Wb[(((size_t)w * 8 + nt) * 4 + kc) * 512 + lane * 8 + j] = v;
        return;
    }
    const int t = blockIdx.x * blockDim.x + threadIdx.x;
    rank[t] = (unsigned short)atomicAdd(&counts[dst[t]], 1);
    {
        const float4 v0 = *(const float4*)(x + (size_t)t * 8);
        const float4 v1 = *(const float4*)(x + (size_t)t * 8 + 4);
        uint4 p;
        p.x = (unsigned)f32_to_bf16_rne(v0.x) | ((unsigned)f32_to_bf16_rne(v0.y) << 16);
        p.y = (unsigned)f32_to_bf16_rne(v0.z) | ((unsigned)f32_to_bf16_rne(v0.w) << 16);
        p.z = (unsigned)f32_to_bf16_rne(v1.x) | ((unsigned)f32_to_bf16_rne(v1.y) << 16);
        p.w = (unsigned)f32_to_bf16_rne(v1.z) | ((unsigned)f32_to_bf16_rne(v1.w) << 16);
        *(uint4*)(xb + (size_t)t * 8) = p;
    }
    if (blockIdx.x == 0 && threadIdx.x < 48) {
        const int rowsel = threadIdx.x >> 4;       // 0,1,2 -> xb,h1,h2
        const int off = threadIdx.x & 15;          // 16 x 16B = 256B row
        unsigned short* zp = (rowsel == 0) ? xb : (rowsel == 1) ? h1 : h2;
        *(uint4*)(zp + (size_t)ZROW * D + off * 8) = make_uint4(0u, 0u, 0u, 0u);
    }
}

// ---------------------------------------------------------------------------
// Scan A: per-block (256-wide) sums of counts -> bsum[196]
// ---------------------------------------------------------------------------
__global__ void block_sum_kernel(const int* __restrict__ counts, int* __restrict__ bsum) {
    __shared__ int red[256];
    const int tid = threadIdx.x;
    const int i = blockIdx.x * 256 + tid;
    red[tid] = (i < N_NODES) ? counts[i] : 0;
    __syncthreads();
    for (int s = 128; s > 0; s >>= 1) {
        if (tid < s) red[tid] += red[tid + s];
        __syncthreads();
    }
    if (tid == 0) bsum[blockIdx.x] = red[0];
}

// ---------------------------------------------------------------------------
// Scan B: exclusive scan of the 196 block sums (single tiny block)
// ---------------------------------------------------------------------------
__global__ void bsum_scan_kernel(const int* __restrict__ bsum,
                                 int* __restrict__ bpre,
                                 int* __restrict__ offsets) {
    __shared__ int s[256];
    const int tid = threadIdx.x;
    const int v = (tid < SCAN_BLOCKS) ? bsum[tid] : 0;
    s[tid] = v;
    __syncthreads();
    for (int off = 1; off < 256; off <<= 1) {
        int a = (tid >= off) ? s[tid - off] : 0;
        __syncthreads();
        s[tid] += a;
        __syncthreads();
    }
    bpre[tid] = s[tid] - v;
    if (tid == 255) offsets[N_NODES] = s[255];
}

// ---------------------------------------------------------------------------
// Scan C: per-block exclusive scan + block prefix -> offsets
// ---------------------------------------------------------------------------
__global__ void offsets_kernel(const int* __restrict__ counts,
                               const int* __restrict__ bpre,
                               int* __restrict__ offsets) {
    __shared__ int s[256];
    const int tid = threadIdx.x;
    const int i = blockIdx.x * 256 + tid;
    const int v = (i < N_NODES) ? counts[i] : 0;
    s[tid] = v;
    __syncthreads();
    for (int off = 1; off < 256; off <<= 1) {
        int a = (tid >= off) ? s[tid - off] : 0;
        __syncthreads();
        s[tid] += a;
        __syncthreads();
    }
    const int excl = s[tid] - v + bpre[blockIdx.x];
    if (i < N_NODES) offsets[i] = excl;
}

// ---------------------------------------------------------------------------
// CSR fill, atomic-free: esrc[offsets[dst[e]] + rank[e]] = src[e]  (ushort)
// ---------------------------------------------------------------------------
__global__ void fill_kernel(const int* __restrict__ src, const int* __restrict__ dst,
                            const unsigned short* __restrict__ rank,
                            const int* __restrict__ offsets,
                            unsigned short* __restrict__ esrc) {
    int e = blockIdx.x * blockDim.x + threadIdx.x;
    if (e < N_EDGES) {
        esrc[offsets[dst[e]] + (int)rank[e]] = (unsigned short)src[e];
    }
}

// ---------------------------------------------------------------------------
// Fused layer: out[v] = (sum h[src_e] - deg[v]*h[v]) @ W^T + deg[v]*b
// Block = 256 threads (4 waves), TN=16 nodes/block, 3125 blocks (best-measured
// geometry, R1). Phase 1 gather: each 32-lane half-wave owns an independent
// 2-node stream (8 half-wave streams/block). Rows read as uint4 (16B, 8
// dims/lane, 16 lanes/row); 8 x 16B row loads in flight per thread. Slots past
// the edge count use the ZROW all-zeros dummy row (L1-hot, adds 0.0) --
// tail-branch-free inner loop. Both nodes' esrc index chunks prefetched
// up-front. Finalize: rowid2==0 lanes -> node A, rowid2==1 -> node B;
// t -> LDS bf16.
// Phase 2: 16x128x128 GEMM via 8 v_mfma_f32_16x16x32_bf16 per wave (all 16
// C-rows used).
// ---------------------------------------------------------------------------
template <bool OUT_BF16>
__global__ __launch_bounds__(256) void gnn_layer_kernel(
    const unsigned short* __restrict__ hb,     // [N+pad][D] bf16, row ZROW = zeros
    const int* __restrict__ offsets,
    const unsigned short* __restrict__ esrc,
    const unsigned short* __restrict__ Wb,     // fragment-ordered bf16 (this layer)
    const float* __restrict__ bias,
    float* __restrict__ outf,
    unsigned short* __restrict__ outb) {

    __shared__ __align__(16) unsigned short tb[TN][TSTR];
    __shared__ float degf[TN];

    const int tid = threadIdx.x;
    const int wave = tid >> 6;
    const int lane = tid & 63;
    const int half = lane >> 5;          // which 32-lane half
    const int l32 = lane & 31;
    const int rowid2 = (lane >> 4) & 1;  // edge parity within slot
    const int d8 = lane & 15;            // dim octet: dims 8*d8 .. 8*d8+7
    const int vbase = blockIdx.x * TN;

    // ---- phase 1: gather (2 nodes per half-wave, serial) ----
    const int j0 = wave * 4 + half * 2;
    const int v0 = vbase + j0;

    const int begA = offsets[v0];
    const int begB = offsets[v0 + 1];
    const int degA = begB - begA;
    const int degB = offsets[v0 + 2] - begB;

    // prefetch both nodes' first index chunks (two loads in flight)
    int idxA = ZROW, idxB = ZROW;
    if (l32 < min(degA, 32)) idxA = (int)esrc[begA + l32];
    if (l32 < min(degB, 32)) idxB = (int)esrc[begB + l32];

    float sA[8], sB[8];
    gather_node(hb, esrc, begA, degA, idxA, l32, rowid2, d8, sA);
    gather_node(hb, esrc, begB, degB, idxB, l32, rowid2, d8, sB);

    // finalize: rowid2==0 lanes -> node A, rowid2==1 lanes -> node B
    {
        const int vv = v0 + rowid2;
        const float dv = (float)(rowid2 ? degB : degA);
        const uint4 r = *(const uint4*)(hb + (size_t)vv * D + 8 * d8);
        float t[8];
#pragma unroll
        for (int k = 0; k < 8; ++k) t[k] = rowid2 ? sB[k] : sA[k];
        t[0] -= dv * bflo(r.x); t[1] -= dv * bfhi(r.x);
        t[2] -= dv * bflo(r.y); t[3] -= dv * bfhi(r.y);
        t[4] -= dv * bflo(r.z); t[5] -= dv * bfhi(r.z);
        t[6] -= dv * bflo(r.w); t[7] -= dv * bfhi(r.w);
        uint4 p;
        p.x = (unsigned)f32_to_bf16_rne(t[0]) | ((unsigned)f32_to_bf16_rne(t[1]) << 16);
        p.y = (unsigned)f32_to_bf16_rne(t[2]) | ((unsigned)f32_to_bf16_rne(t[3]) << 16);
        p.z = (unsigned)f32_to_bf16_rne(t[4]) | ((unsigned)f32_to_bf16_rne(t[5]) << 16);
        p.w = (unsigned)f32_to_bf16_rne(t[6]) | ((unsigned)f32_to_bf16_rne(t[7]) << 16);
        *(uint4*)&tb[j0 + rowid2][8 * d8] = p;
        if (d8 == 0) degf[j0 + rowid2] = dv;
    }
    __syncthreads();

    // ---- phase 2: MFMA GEMM  out[16][128] = t[16][128] @ Wt[128][128] ----
    const int n16 = lane & 15;
    const int quad = lane >> 4;

    bf16x8 afrag[4];
#pragma unroll
    for (int kc = 0; kc < 4; ++kc)
        afrag[kc] = *(const bf16x8*)&tb[n16][kc * 32 + quad * 8];

#pragma unroll
    for (int i = 0; i < 2; ++i) {
        const int nt = wave * 2 + i;
        f32x4 acc = {0.f, 0.f, 0.f, 0.f};
#pragma unroll
        for (int kc = 0; kc < 4; ++kc) {
            const bf16x8 bfrag = *(const bf16x8*)&Wb[((nt * 4 + kc) * 64 + lane) * 8];
            acc = __builtin_amdgcn_mfma_f32_16x16x32_bf16(afrag[kc], bfrag, acc, 0, 0, 0);
        }
        const int o = nt * 16 + n16;
        const float bo = bias[o];
#pragma unroll
        for (int r = 0; r < 4; ++r) {
            const int m = quad * 4 + r;
            const float val = acc[r] + degf[m] * bo;
            if (OUT_BF16)
                outb[(size_t)(vbase + m) * D + o] = f32_to_bf16_rne(val);
            else
                outf[(size_t)(vbase + m) * D + o] = val;
        }
    }
}

extern "C" void kernel_launch(void* const* d_in, const int* in_sizes, int n_in,
                              void* d_out, int out_size, void* d_ws, size_t ws_size,
                              hipStream_t stream) {
    const float* x  = (const float*)d_in[0];
    const float* W1 = (const float*)d_in[1];
    const float* b1 = (const float*)d_in[2];
    const float* W2 = (const float*)d_in[3];
    const float* b2 = (const float*)d_in[4];
    const float* W3 = (const float*)d_in[5];
    const float* b3 = (const float*)d_in[6];
    const int*   ei = (const int*)d_in[7];      // [2, E] int32
    // d_in[8] = edge_index_inter — unused by the reference

    const int* src = ei;            // row 0
    const int* dst = ei + N_EDGES;  // row 1
    float* out = (float*)d_out;

    // workspace layout (256B-aligned slabs); h-buffers have +2 rows for ZROW
    const size_t HSLAB = (size_t)(N_NODES + 2) * D * 2;
    char* ws = (char*)d_ws;
    int* counts  = (int*)ws;                          ws += 204800;               // N ints
    int* offsets = (int*)ws;                          ws += 204800;               // N+1 ints
    int* bsum    = (int*)ws;                          ws += 1024;
    int* bpre    = (int*)ws;                          ws += 1024;
    unsigned short* rank = (unsigned short*)ws;       ws += (size_t)N_EDGES * 2;  // 1.6MB
    unsigned short* esrc = (unsigned short*)ws;       ws += (size_t)N_EDGES * 2;  // 1.6MB
    unsigned short* Wb = (unsigned short*)ws;         ws += 3 * 16384 * 2;        // 96KB
    unsigned short* xb = (unsigned short*)ws;         ws += HSLAB;
    unsigned short* h1 = (unsigned short*)ws;         ws += HSLAB;
    unsigned short* h2 = (unsigned short*)ws;

    // ---- CSR build + cvt + weight pack ----
    hipMemsetAsync(counts, 0, N_NODES * sizeof(int), stream);
    prep_kernel<<<EDGE_BLOCKS + 192, 256, 0, stream>>>(dst, counts, rank, x, xb, h1, h2,
                                                       W1, W2, W3, Wb);
    block_sum_kernel<<<SCAN_BLOCKS, 256, 0, stream>>>(counts, bsum);
    bsum_scan_kernel<<<1, 256, 0, stream>>>(bsum, bpre, offsets);
    offsets_kernel<<<SCAN_BLOCKS, 256, 0, stream>>>(counts, bpre, offsets);
    fill_kernel<<<(N_EDGES + 255) / 256, 256, 0, stream>>>(src, dst, rank, offsets, esrc);

    const int blocks = N_NODES / TN;   // 3125

    gnn_layer_kernel<true ><<<blocks, 256, 0, stream>>>(xb, offsets, esrc, Wb,          b1, nullptr, h1);
    gnn_layer_kernel<true ><<<blocks, 256, 0, stream>>>(h1, offsets, esrc, Wb + 16384,  b2, nullptr, h2);
    gnn_layer_kernel<false><<<blocks, 256, 0, stream>>>(h2, offsets, esrc, Wb + 32768,  b3, out, nullptr);
}